// Round 1
// baseline (172.022 us; speedup 1.0000x reference)
//
#include <hip/hip_runtime.h>
#include <hip/hip_bf16.h>

#define BATCH    64
#define IN_CH    128
#define ILEN     512
#define KW       8
#define OLEN     505
#define OCH      128
#define KDIM     1024   // IN_CH*KW
#define BK       128
#define NCHUNK   8      // KDIM/BK
#define NTHREADS 512

using f32x4  = __attribute__((ext_vector_type(4))) float;
using bf16x8 = __attribute__((ext_vector_type(8))) short;
using s16x4  = __attribute__((ext_vector_type(4))) short;

__device__ __forceinline__ short f2bf(float f) {
  union { __hip_bfloat16 h; short s; } u;
  u.h = __float2bfloat16(f);
  return u.s;
}

// out[b][o][l] = sum_{i,k} x[b][i][l+k] * w[l][o][i*8+k] + bias[o][l]
// Per block (fixed l): GEMM M=64(b) x N=128(o) x K=1024(ik).
// A[b][ik] = x[b][ik>>3][l + (ik&7)]   (staged bf16, XOR-swizzled LDS)
// B[o][ik] = w[l][o][ik]               (N x K row-major = B^T input form)
__global__ __launch_bounds__(NTHREADS, 4) void lc1d_mfma(
    const float* __restrict__ x, const float* __restrict__ w,
    const float* __restrict__ bias, float* __restrict__ out) {
  const int l    = blockIdx.x;
  const int tid  = threadIdx.x;
  const int lane = tid & 63;
  const int wid  = tid >> 6;   // 0..7 : wave's 16-col group of N
  const int r    = lane & 15;
  const int h    = lane >> 4;

  __shared__ short As[BATCH * BK];  // 16 KB, swizzled: idx = b*BK + (col ^ ((b&7)<<3))
  __shared__ short Bs[OCH * BK];    // 32 KB, same swizzle on o

  f32x4 acc[4];
#pragma unroll
  for (int m = 0; m < 4; ++m) acc[m] = (f32x4){0.f, 0.f, 0.f, 0.f};

  const float* __restrict__ wl = w + (size_t)l * (OCH * KDIM);

  // B staging geometry: element group f32x4; per it: o = it*16 + to, col = jj
  const int to = tid >> 5;           // 0..15
  const int jj = (tid & 31) * 4;     // 0..124
  const int sB = (to & 7) << 3;      // swizzle const per thread (it*16 ≡ 0 mod 8)
  // A staging geometry: per it: b = it*4 + tb, col = kk
  const int kk  = tid & 127;
  const int tb  = tid >> 7;          // 0..3
  const int ib  = kk >> 3;           // local i within chunk
  const int kof = kk & 7;

  f32x4 bb[8];
  float aa[16];

  auto loadB = [&](int kc) {
#pragma unroll
    for (int it = 0; it < 8; ++it)
      bb[it] = *reinterpret_cast<const f32x4*>(
          wl + (size_t)(it * 16 + to) * KDIM + kc * BK + jj);
  };
  auto loadA = [&](int kc) {
    const float* xb = x + (size_t)(kc * 16 + ib) * ILEN + l + kof;
#pragma unroll
    for (int it = 0; it < 16; ++it)
      aa[it] = xb[(size_t)(it * 4 + tb) * (IN_CH * ILEN)];
  };

  loadB(0);
  loadA(0);

  for (int kc = 0; kc < NCHUNK; ++kc) {
    __syncthreads();  // previous MFMA phase done reading LDS
    // ---- store staged regs to LDS as bf16 (swizzled) ----
#pragma unroll
    for (int it = 0; it < 8; ++it) {
      const int o = it * 16 + to;
      s16x4 v;
      v[0] = f2bf(bb[it][0]); v[1] = f2bf(bb[it][1]);
      v[2] = f2bf(bb[it][2]); v[3] = f2bf(bb[it][3]);
      *reinterpret_cast<s16x4*>(&Bs[o * BK + (jj ^ sB)]) = v;
    }
#pragma unroll
    for (int it = 0; it < 16; ++it) {
      const int b = it * 4 + tb;
      As[b * BK + (kk ^ ((b & 7) << 3))] = f2bf(aa[it]);
    }
    __syncthreads();  // LDS ready
    // ---- prefetch next chunk into regs (hides HBM latency under MFMA) ----
    if (kc + 1 < NCHUNK) { loadB(kc + 1); loadA(kc + 1); }
    // ---- MFMA phase ----
    const int sw = (r & 7) << 3;
#pragma unroll
    for (int ks = 0; ks < 4; ++ks) {
      const int koff = ks * 32 + h * 8;
      const bf16x8 bfr = *reinterpret_cast<const bf16x8*>(
          &Bs[(wid * 16 + r) * BK + (koff ^ sw)]);
#pragma unroll
      for (int mt = 0; mt < 4; ++mt) {
        const bf16x8 afr = *reinterpret_cast<const bf16x8*>(
            &As[(mt * 16 + r) * BK + (koff ^ sw)]);
        acc[mt] = __builtin_amdgcn_mfma_f32_16x16x32_bf16(afr, bfr, acc[mt], 0, 0, 0);
      }
    }
  }

  // ---- epilogue: C/D layout col=lane&15 (o), row=(lane>>4)*4+j (b) ----
  const int o = wid * 16 + r;
  const float bv = bias[o * OLEN + l];
#pragma unroll
  for (int mt = 0; mt < 4; ++mt) {
#pragma unroll
    for (int j = 0; j < 4; ++j) {
      const int b = mt * 16 + h * 4 + j;
      out[(size_t)b * (OCH * OLEN) + o * OLEN + l] = acc[mt][j] + bv;
    }
  }
}

extern "C" void kernel_launch(void* const* d_in, const int* in_sizes, int n_in,
                              void* d_out, int out_size, void* d_ws, size_t ws_size,
                              hipStream_t stream) {
  const float* x    = (const float*)d_in[0];
  const float* w    = (const float*)d_in[1];
  const float* bias = (const float*)d_in[2];
  float* out        = (float*)d_out;
  lc1d_mfma<<<dim3(OLEN), dim3(NTHREADS), 0, stream>>>(x, w, bias, out);
}